// Round 9
// baseline (174.956 us; speedup 1.0000x reference)
//
#include <hip/hip_runtime.h>
#include <hip/hip_bf16.h>

#define N_ROWS 131072
#define K_MIX  256
#define D_DIM  128
#define LOG2E 1.4426950408889634f
#define LN2   0.6931471805599453f

typedef float  f32x4  __attribute__((ext_vector_type(4)));
typedef short  bf16x8 __attribute__((ext_vector_type(8)));

__device__ inline bf16x8 pack8(float4 a, float4 b) {
    union { bf16x8 v; __hip_bfloat162 h[4]; } u;
    u.h[0] = __float22bfloat162_rn(make_float2(a.x, a.y));
    u.h[1] = __float22bfloat162_rn(make_float2(a.z, a.w));
    u.h[2] = __float22bfloat162_rn(make_float2(b.x, b.y));
    u.h[3] = __float22bfloat162_rn(make_float2(b.z, b.w));
    return u.v;
}

// ---- prep 1: msq[col] = -0.5*log2e * sum_d prec[d]*mu[col][d]^2 ----
__global__ void prep_musq(const float* __restrict__ mu, const float* __restrict__ prec,
                          float* __restrict__ msq)
{
    int col = threadIdx.x;
    const float4* m4 = (const float4*)(mu + (size_t)col * D_DIM);
    const float4* p4 = (const float4*)prec;
    float s = 0.f;
    #pragma unroll 8
    for (int i = 0; i < 32; ++i) {
        float4 m = m4[i], p = p4[i];
        s += p.x*m.x*m.x + p.y*m.y*m.y + p.z*m.z*m.z + p.w*m.w*m.w;
    }
    msq[col] = -0.5f * LOG2E * s;
}

// ---- prep 2: Bf in MFMA B-fragment order: frag(w,k,cg,lane) = bf16x8 ----
// col = w*64 + cg*16 + (lane&15), d = k*32 + (lane>>4)*8 + 0..7, val = log2e*prec*mu
__global__ void prep_frag(const float* __restrict__ mu, const float* __restrict__ prec,
                          unsigned short* __restrict__ Bf)
{
    int g = blockIdx.x * 256 + threadIdx.x;       // 0..4095
    int lane = g & 63, cg = (g >> 6) & 3, k = (g >> 8) & 3, w = (g >> 10) & 3;
    int col = w*64 + cg*16 + (lane & 15);
    int d0 = k*32 + (lane >> 4)*8;
    const float* mp = mu + (size_t)col * D_DIM + d0;
    const float* pp = prec + d0;
    union { bf16x8 v; __hip_bfloat162 h[4]; } u;
    #pragma unroll
    for (int j = 0; j < 4; ++j) {
        float e0 = LOG2E * pp[2*j]     * mp[2*j];
        float e1 = LOG2E * pp[2*j + 1] * mp[2*j + 1];
        u.h[j] = __float22bfloat162_rn(make_float2(e0, e1));
    }
    *(bf16x8*)(Bf + (size_t)g * 8) = u.v;
}

// ---------------- main: 256 thr, 4 waves x 64 cols, 8 tiles of 32 rows ----------------
__global__ __launch_bounds__(256, 4)
void mixture_main(const float* __restrict__ x,
                  const unsigned short* __restrict__ Bf,
                  const float* __restrict__ msq,
                  const float* __restrict__ prec,
                  float* __restrict__ out)
{
    __shared__ __align__(16) float sXT[2][4096];   // two 16-KB x tiles (granule-swizzled)
    __shared__ float sMS[4 * 32 * 2];              // [wave][row][(m,s)]
    __shared__ float sPrec[D_DIM];

    const int tid  = threadIdx.x;
    const int lane = tid & 63;
    const int w    = tid >> 6;
    const int low4 = lane & 15;
    const int q    = lane >> 4;

    // ---- B fragments -> registers, issued FIRST (vmcnt ordering) ----
    bf16x8 Bfr[4][4];
    #pragma unroll
    for (int k = 0; k < 4; ++k)
        #pragma unroll
        for (int cg = 0; cg < 4; ++cg)
            Bfr[k][cg] = *(const bf16x8*)(Bf + (size_t)(((w*4 + k)*4 + cg)*64 + lane) * 8);
    float mneg[4];
    #pragma unroll
    for (int cg = 0; cg < 4; ++cg) mneg[cg] = msq[w*64 + cg*16 + low4];

    if (tid < D_DIM) sPrec[tid] = prec[tid];

    // ---- per-lane DMA offsets (tile-invariant). Swizzle: pos p of row r holds
    // global granule (p-r)&31; DMA instr j covers rows 2j,2j+1, p = lane&31.
    int goff[4], loff[4];
    {
        int p = lane & 31;
        #pragma unroll
        for (int jj = 0; jj < 4; ++jj) {
            int j = w*4 + jj;
            int r = 2*j + (lane >> 5);
            goff[jj] = r*512 + (((p - r) & 31) << 4);
            loff[jj] = j*1024 + lane*16;
        }
    }
    const char* gtile = (const char*)x + (size_t)blockIdx.x * 131072;  // 256 rows * 512 B
    char* lbase = (char*)&sXT[0][0];

    // issue DMA for tiles 0 and 1 (after B/mneg loads)
    #pragma unroll
    for (int jj = 0; jj < 4; ++jj)
        __builtin_amdgcn_global_load_lds(
            (const __attribute__((address_space(1))) unsigned int*)(gtile + goff[jj]),
            (__attribute__((address_space(3))) unsigned int*)(lbase + loff[jj]), 16, 0, 0);
    #pragma unroll
    for (int jj = 0; jj < 4; ++jj)
        __builtin_amdgcn_global_load_lds(
            (const __attribute__((address_space(1))) unsigned int*)(gtile + 16384 + goff[jj]),
            (__attribute__((address_space(3))) unsigned int*)(lbase + 16384 + loff[jj]), 16, 0, 0);

    float lacc = 0.f;

    #pragma unroll 1
    for (int t = 0; t < 8; ++t) {
        // own DMA for tile t retired (t+1 stays in flight) + lgkm drained, then barrier
        if (t < 7) __builtin_amdgcn_s_waitcnt(0x0F74);   // vmcnt(4)
        else       __builtin_amdgcn_s_waitcnt(0x0F70);   // vmcnt(0)
        __builtin_amdgcn_s_waitcnt(0xC07F);              // lgkmcnt(0)
        __asm__ volatile("s_barrier" ::: "memory");

        const float* buf = &sXT[t & 1][0];

        f32x4 acc[2][4];
        #pragma unroll
        for (int cg = 0; cg < 4; ++cg) {
            #pragma unroll
            for (int i = 0; i < 4; ++i) { acc[0][cg][i] = mneg[cg]; acc[1][cg][i] = mneg[cg]; }
        }

        float xs = 0.f;
        #pragma unroll
        for (int k = 0; k < 4; ++k) {
            int g0  = 8*k + 2*q;
            int p0  = (g0 + low4) & 31;
            int p1  = (g0 + 1 + low4) & 31;
            int p0b = (p0 + 16) & 31;
            int p1b = (p1 + 16) & 31;
            const float* r0 = buf + low4 * 128;
            const float* r1 = buf + (low4 + 16) * 128;
            float4 u0 = *(const float4*)(r0 + p0  * 4);
            float4 u1 = *(const float4*)(r0 + p1  * 4);
            float4 v0 = *(const float4*)(r1 + p0b * 4);
            float4 v1 = *(const float4*)(r1 + p1b * 4);
            if (w == 0) {   // wave 0 covers every (row,dim) of the tile exactly once
                float4 pa = *(const float4*)&sPrec[k*32 + q*8];
                float4 pb = *(const float4*)&sPrec[k*32 + q*8 + 4];
                xs += pa.x*u0.x*u0.x + pa.y*u0.y*u0.y + pa.z*u0.z*u0.z + pa.w*u0.w*u0.w
                    + pb.x*u1.x*u1.x + pb.y*u1.y*u1.y + pb.z*u1.z*u1.z + pb.w*u1.w*u1.w
                    + pa.x*v0.x*v0.x + pa.y*v0.y*v0.y + pa.z*v0.z*v0.z + pa.w*v0.w*v0.w
                    + pb.x*v1.x*v1.x + pb.y*v1.y*v1.y + pb.z*v1.z*v1.z + pb.w*v1.w*v1.w;
            }
            bf16x8 a0 = pack8(u0, u1);
            bf16x8 a1 = pack8(v0, v1);
            #pragma unroll
            for (int cg = 0; cg < 4; ++cg) {
                acc[0][cg] = __builtin_amdgcn_mfma_f32_16x16x32_bf16(a0, Bfr[k][cg], acc[0][cg], 0, 0, 0);
                acc[1][cg] = __builtin_amdgcn_mfma_f32_16x16x32_bf16(a1, Bfr[k][cg], acc[1][cg], 0, 0, 0);
            }
        }
        lacc += 0.5f * xs;   // nonzero only in wave 0

        // ---- per-row (m,s) over this wave's 64 cols; write to sMS ----
        #pragma unroll
        for (int m = 0; m < 2; ++m) {
            #pragma unroll
            for (int i = 0; i < 4; ++i) {
                float v0 = acc[m][0][i], v1 = acc[m][1][i];
                float v2 = acc[m][2][i], v3 = acc[m][3][i];
                float mx = fmaxf(fmaxf(v0, v1), fmaxf(v2, v3));
                float ss = __builtin_amdgcn_exp2f(v0 - mx) + __builtin_amdgcn_exp2f(v1 - mx)
                         + __builtin_amdgcn_exp2f(v2 - mx) + __builtin_amdgcn_exp2f(v3 - mx);
                #pragma unroll
                for (int st = 1; st <= 8; st <<= 1) {
                    float mo = __shfl_xor(mx, st);
                    float so = __shfl_xor(ss, st);
                    // one-exp merge: e = 2^{-|mx-mo|}
                    float d  = mo - mx;
                    float e  = __builtin_amdgcn_exp2f(-fabsf(d));
                    bool  o  = d > 0.f;
                    ss = o ? (ss * e + so) : (ss + so * e);
                    mx = o ? mo : mx;
                }
                if (low4 == 0) {
                    int row = m*16 + q*4 + i;
                    *(float2*)&sMS[(w*32 + row)*2] = make_float2(mx, ss);
                }
            }
        }

        __builtin_amdgcn_s_waitcnt(0xC07F);              // lgkmcnt(0): sMS visible
        __asm__ volatile("s_barrier" ::: "memory");      // also: all packs of tile t done

        if (t < 6) {   // refill the just-freed buffer with tile t+2
            #pragma unroll
            for (int jj = 0; jj < 4; ++jj)
                __builtin_amdgcn_global_load_lds(
                    (const __attribute__((address_space(1))) unsigned int*)(gtile + (size_t)(t+2)*16384 + goff[jj]),
                    (__attribute__((address_space(3))) unsigned int*)(lbase + (t & 1)*16384 + loff[jj]), 16, 0, 0);
        }

        if (tid < 32) {   // merge the 4 waves' (m,s) for row=tid, accumulate lse
            float2 a = *(const float2*)&sMS[(0*32 + tid)*2];
            float2 b = *(const float2*)&sMS[(1*32 + tid)*2];
            float2 c = *(const float2*)&sMS[(2*32 + tid)*2];
            float2 d = *(const float2*)&sMS[(3*32 + tid)*2];
            float mx = fmaxf(fmaxf(a.x, b.x), fmaxf(c.x, d.x));
            float ss = a.y * __builtin_amdgcn_exp2f(a.x - mx)
                     + b.y * __builtin_amdgcn_exp2f(b.x - mx)
                     + c.y * __builtin_amdgcn_exp2f(c.x - mx)
                     + d.y * __builtin_amdgcn_exp2f(d.x - mx);
            lacc -= LN2 * (mx + __builtin_amdgcn_logf(ss));
        }
    }

    // ---- every contribution lives in wave 0 ----
    if (w == 0) {
        lacc += __shfl_xor(lacc, 32); lacc += __shfl_xor(lacc, 16);
        lacc += __shfl_xor(lacc, 8);  lacc += __shfl_xor(lacc, 4);
        lacc += __shfl_xor(lacc, 2);  lacc += __shfl_xor(lacc, 1);
        if (lane == 0) atomicAdd(out, lacc);
    }
}

extern "C" void kernel_launch(void* const* d_in, const int* in_sizes, int n_in,
                              void* d_out, int out_size, void* d_ws, size_t ws_size,
                              hipStream_t stream) {
    const float* x    = (const float*)d_in[0];
    const float* mu   = (const float*)d_in[1];
    const float* prec = (const float*)d_in[2];
    float* out = (float*)d_out;

    unsigned short* Bf = (unsigned short*)d_ws;                 // 65536 B
    float* msq = (float*)((char*)d_ws + 65536);                 // +1024 B

    hipMemsetAsync(d_out, 0, sizeof(float), stream);
    prep_musq<<<1, 256, 0, stream>>>(mu, prec, msq);
    prep_frag<<<16, 256, 0, stream>>>(mu, prec, Bf);
    mixture_main<<<N_ROWS / 256, 256, 0, stream>>>(x, Bf, msq, prec, out);
}